// Round 1
// baseline (1116.643 us; speedup 1.0000x reference)
//
#include <hip/hip_runtime.h>
#include <hip/hip_bf16.h>

using bf16 = __hip_bfloat16;
typedef __attribute__((ext_vector_type(8))) short short8;
typedef __attribute__((ext_vector_type(4))) float floatx4;

#define MFMA(a,b,c) __builtin_amdgcn_mfma_f32_16x16x32_bf16(a,b,c,0,0,0)

static __device__ __forceinline__ unsigned short f2bb(float f){
    union { __hip_bfloat16 h; unsigned short u; } cv;
    cv.h = __float2bfloat16(f);
    return cv.u;
}

// ---------------- convert fp32 -> bf16 (vectorized) ----------------
__global__ __launch_bounds__(256) void conv_kernel(const float* __restrict__ in,
                                                   bf16* __restrict__ out, int n4){
    int i = blockIdx.x*256 + threadIdx.x;
    if (i < n4){
        float4 v = ((const float4*)in)[i];
        uint2 p;
        p.x = (unsigned)f2bb(v.x) | ((unsigned)f2bb(v.y) << 16);
        p.y = (unsigned)f2bb(v.z) | ((unsigned)f2bb(v.w) << 16);
        ((uint2*)out)[i] = p;
    }
}

// ---------------- weight transpose fp32[K][N] -> bf16[N][K] ----------------
__global__ __launch_bounds__(256) void wtrans_kernel(const float* __restrict__ in,
                                                     bf16* __restrict__ out, int K, int N){
    __shared__ float t[32][33];
    int z = blockIdx.z;
    in  += (size_t)z*K*N;
    out += (size_t)z*K*N;
    int n0 = blockIdx.x*32, k0 = blockIdx.y*32;
    int tx = threadIdx.x, ty = threadIdx.y;
    #pragma unroll
    for (int j=0;j<32;j+=8) t[ty+j][tx] = in[(size_t)(k0+ty+j)*N + n0+tx];
    __syncthreads();
    #pragma unroll
    for (int j=0;j<32;j+=8) out[(size_t)(n0+ty+j)*K + k0+tx] = __float2bfloat16(t[tx][ty+j]);
}

// ---------------- LayerNorm, row = 512 floats, out bf16 ----------------
__global__ __launch_bounds__(256) void ln_kernel(const float* __restrict__ x,
                                                 const float* __restrict__ g,
                                                 const float* __restrict__ bta,
                                                 bf16* __restrict__ out){
    int row = blockIdx.x;
    const float* xr = x + (size_t)row*512;
    int tid = threadIdx.x;
    float v0 = xr[tid], v1 = xr[tid+256];
    float s = v0 + v1;
    #pragma unroll
    for (int o=1;o<64;o<<=1) s += __shfl_xor(s, o);
    __shared__ float red[8];
    if ((tid&63)==0) red[tid>>6] = s;
    __syncthreads();
    float mean = (red[0]+red[1]+red[2]+red[3]) * (1.0f/512.0f);
    float d0 = v0-mean, d1 = v1-mean;
    float vs = d0*d0 + d1*d1;
    #pragma unroll
    for (int o=1;o<64;o<<=1) vs += __shfl_xor(vs, o);
    if ((tid&63)==0) red[4 + (tid>>6)] = vs;
    __syncthreads();
    float var = (red[4]+red[5]+red[6]+red[7]) * (1.0f/512.0f);
    float rstd = rsqrtf(var + 1e-6f);
    out[(size_t)row*512 + tid]     = __float2bfloat16(d0*rstd*g[tid]     + bta[tid]);
    out[(size_t)row*512 + tid+256] = __float2bfloat16(d1*rstd*g[tid+256] + bta[tid+256]);
}

// ---------------- guider keys: gk[b][g][h*128+e] fp32 ----------------
__global__ __launch_bounds__(256) void gk_kernel(const float* __restrict__ guider,
                                                 const float* __restrict__ Wkg,
                                                 float* __restrict__ gk){
    int b = blockIdx.x>>2, g = blockIdx.x&3, m = g>>1;
    __shared__ float xr[512];
    int tid = threadIdx.x;
    xr[tid]     = guider[((size_t)b*4+g)*512 + tid];
    xr[tid+256] = guider[((size_t)b*4+g)*512 + tid+256];
    __syncthreads();
    const float* W = Wkg + (size_t)m*512*1024;
    float a0=0,a1=0,a2=0,a3=0;
    for (int d=0; d<512; d++){
        float xv = xr[d];
        const float* wr = W + (size_t)d*1024 + tid;
        a0 += xv*wr[0]; a1 += xv*wr[256]; a2 += xv*wr[512]; a3 += xv*wr[768];
    }
    float* o = gk + ((size_t)b*4+g)*1024 + tid;
    o[0]=a0; o[256]=a1; o[512]=a2; o[768]=a3;
}

// ---------------- guider attention: g_att[b][h][t][4] fp32 ----------------
__global__ __launch_bounds__(256) void gatt_kernel(const bf16* __restrict__ qs,
                                                   const float* __restrict__ gk,
                                                   const int* __restrict__ gmask,
                                                   float* __restrict__ gatt){
    int idx = blockIdx.x*256 + threadIdx.x;        // (b*8+h)*512 + t
    int b = idx>>12, t = idx&511;
    int h = (idx>>9)&7;
    const bf16* q = qs + ((size_t)idx)*128;
    float s[4];
    #pragma unroll
    for (int g=0; g<4; g++){
        const float* kk = gk + ((size_t)b*4+g)*1024 + h*128;
        float a = 0.f;
        for (int d=0; d<128; d++) a += __bfloat162float(q[d]) * kk[d];
        s[g] = a;
    }
    const int* gm = gmask + ((size_t)b*512 + t)*4;
    float mx = -3.4e38f;
    #pragma unroll
    for (int g=0; g<4; g++){ if (gm[g]==0) s[g] = -1e9f; mx = fmaxf(mx, s[g]); }
    float sum = 0.f;
    #pragma unroll
    for (int g=0; g<4; g++){ s[g] = __expf(s[g]-mx); sum += s[g]; }
    float inv = 1.0f/sum;
    float* o = gatt + (size_t)idx*4;
    #pragma unroll
    for (int g=0; g<4; g++) o[g] = s[g]*inv;
}

// ---------------- generic 128x128 bf16 MFMA GEMM, C = A @ Bt^T ----------------
// A: [M][K] bf16 (k-contig), Bt: [N][K] bf16 (k-contig). blockIdx.z = modality.
// EPI 0: qs bf16 [B,H,T,DK] scaled 1/sqrt(128)
// EPI 1: lk bf16 [M,S,B,H,L,DK]
// EPI 2: lv^T bf16 [M,S,B,H,DV,L]
// EPI 3: out fp32 = acc + resid
template<int EPI>
__global__ __launch_bounds__(256)
void gemm_k(const bf16* __restrict__ A, const bf16* __restrict__ Bt,
            void* __restrict__ Cout, const float* __restrict__ resid,
            int M, int N, int K)
{
    int mz = blockIdx.z;
    A  += (size_t)mz * M * K;
    Bt += (size_t)mz * N * K;
    int m0 = blockIdx.y * 128, n0 = blockIdx.x * 128;
    __shared__ alignas(16) bf16 As[8192];   // [kb2][rb8][kg4][m16][j8]
    __shared__ alignas(16) bf16 Bs[8192];
    int tid = threadIdx.x;
    int wave = tid >> 6, lane = tid & 63, kg = lane >> 4, lm = lane & 15;
    int wr = wave >> 1, wc = wave & 1;
    floatx4 acc[4][4];
    #pragma unroll
    for (int i=0;i<4;i++)
        #pragma unroll
        for (int j=0;j<4;j++) acc[i][j] = (floatx4){0.f,0.f,0.f,0.f};

    for (int k0 = 0; k0 < K; k0 += 64){
        __syncthreads();
        #pragma unroll
        for (int i=0;i<4;i++){
            int idx = tid + i*256;
            int row = idx >> 3, kc = idx & 7;
            int lo = ((((kc>>2)*8 + (row>>4))*4 + (kc&3))*16 + (row&15))*8;
            *(short8*)(As + lo) = *(const short8*)(A  + (size_t)(m0+row)*K + k0 + kc*8);
            *(short8*)(Bs + lo) = *(const short8*)(Bt + (size_t)(n0+row)*K + k0 + kc*8);
        }
        __syncthreads();
        #pragma unroll
        for (int kb=0;kb<2;kb++){
            short8 af[4], bfr[4];
            #pragma unroll
            for (int i=0;i<4;i++){
                af[i]  = *(const short8*)(As + (((kb*8 + wr*4+i)*4 + kg)*16 + lm)*8);
                bfr[i] = *(const short8*)(Bs + (((kb*8 + wc*4+i)*4 + kg)*16 + lm)*8);
            }
            #pragma unroll
            for (int i=0;i<4;i++)
                #pragma unroll
                for (int j=0;j<4;j++)
                    acc[i][j] = MFMA(af[i], bfr[j], acc[i][j]);
        }
    }
    #pragma unroll
    for (int i=0;i<4;i++){
        #pragma unroll
        for (int j=0;j<4;j++){
            int row0 = m0 + wr*64 + i*16 + kg*4;
            int col  = n0 + wc*64 + j*16 + lm;
            if constexpr (EPI == 2){
                int s = row0 >> 12, b = (row0 >> 9) & 7, l = row0 & 511;
                int h = col >> 7, e = col & 127;
                size_t off = ((((size_t)(mz*2+s)*8+b)*8+h)*128 + e)*512 + l;
                uint2 pk;
                pk.x = (unsigned)f2bb(acc[i][j][0]) | ((unsigned)f2bb(acc[i][j][1])<<16);
                pk.y = (unsigned)f2bb(acc[i][j][2]) | ((unsigned)f2bb(acc[i][j][3])<<16);
                *(uint2*)((bf16*)Cout + off) = pk;
            } else {
                #pragma unroll
                for (int r=0;r<4;r++){
                    int row = row0 + r;
                    float v = acc[i][j][r];
                    if constexpr (EPI == 0){
                        int b = row>>9, t = row&511, h = col>>7, dk = col&127;
                        ((bf16*)Cout)[((size_t)(b*8+h)*512 + t)*128 + dk] =
                            __float2bfloat16(v*0.08838834764831845f);
                    } else if constexpr (EPI == 1){
                        int s = row>>12, b = (row>>9)&7, l = row&511;
                        int h = col>>7, dk = col&127;
                        ((bf16*)Cout)[((((size_t)(mz*2+s)*8+b)*8+h)*512 + l)*128 + dk] =
                            __float2bfloat16(v);
                    } else {
                        ((float*)Cout)[(size_t)row*512 + col] = v + resid[(size_t)row*512 + col];
                    }
                }
            }
        }
    }
}

// ---------------- fused per-chunk attention ----------------
// One block = (b,h) and 32 Q rows. 4 chunks of L=512 each: S=QK^T in regs,
// register softmax (cross-wave LDS reduce), final_att -> d_out, P -> swizzled
// LDS -> A-frags, O += P@V. K/V B-frags read directly from global.
__global__ __launch_bounds__(256)
void attn_kernel(const bf16* __restrict__ qs, const bf16* __restrict__ lk,
                 const bf16* __restrict__ lvt, const float* __restrict__ gatt,
                 const int* __restrict__ lmask, float* __restrict__ fa,
                 bf16* __restrict__ oh)
{
    __shared__ alignas(16) float Ss[32*512];   // 64 KB; transient redbuf + P buffer
    int blk = blockIdx.x;
    // XCD-aware swizzle: all 16 t-blocks of a (b,h) land on the same XCD (%8)
    int xcd = blk & 7;
    int rest = blk >> 3;
    int tblk = rest & 15;
    int bh = (rest >> 4)*8 + xcd;              // 0..63
    int h = bh & 7, b = bh >> 3;
    int t0 = tblk * 32;
    int tid = threadIdx.x, w = tid>>6, lane = tid&63, kg = lane>>4, lm = lane&15;

    // Q fragments in registers (A-operand): qf[kb][rb]
    const bf16* qbase = qs + ((size_t)bh*512 + t0)*128;
    short8 qf[4][2];
    #pragma unroll
    for (int kb=0;kb<4;kb++)
        #pragma unroll
        for (int rb=0;rb<2;rb++)
            qf[kb][rb] = *(const short8*)(qbase + (size_t)(rb*16+lm)*128 + kb*32 + kg*8);

    floatx4 oacc[2][2];
    #pragma unroll
    for (int rb=0;rb<2;rb++)
        #pragma unroll
        for (int nbi=0;nbi<2;nbi++) oacc[rb][nbi] = (floatx4){0.f,0.f,0.f,0.f};

    for (int c=0;c<4;c++){
        __syncthreads();                        // Ss reuse guard
        const bf16* kbase = lk + ((size_t)(c*8+b)*8 + h)*512*128;
        floatx4 sacc[2][8];
        #pragma unroll
        for (int rb=0;rb<2;rb++)
            #pragma unroll
            for (int nbi=0;nbi<8;nbi++) sacc[rb][nbi] = (floatx4){0.f,0.f,0.f,0.f};
        // S = Q @ K^T  (wave w owns cols w*128 .. w*128+127)
        #pragma unroll
        for (int kb=0;kb<4;kb++){
            #pragma unroll
            for (int nbi=0;nbi<8;nbi++){
                int l = w*128 + nbi*16 + lm;
                short8 kf = *(const short8*)(kbase + (size_t)l*128 + kb*32 + kg*8);
                sacc[0][nbi] = MFMA(qf[kb][0], kf, sacc[0][nbi]);
                sacc[1][nbi] = MFMA(qf[kb][1], kf, sacc[1][nbi]);
            }
        }
        // mask
        const int* mbase = lmask + ((size_t)(c*8+b)*512 + t0)*512;
        #pragma unroll
        for (int rb=0;rb<2;rb++)
            #pragma unroll
            for (int nbi=0;nbi<8;nbi++)
                #pragma unroll
                for (int r=0;r<4;r++){
                    int row = rb*16+kg*4+r, col = w*128+nbi*16+lm;
                    if (mbase[(size_t)row*512 + col] == 0) sacc[rb][nbi][r] = -1e9f;
                }
        // row max: per-lane over nbi, then across the 16 lanes of a row, then cross-wave
        float rmax[2][4];
        #pragma unroll
        for (int rb=0;rb<2;rb++)
            #pragma unroll
            for (int r=0;r<4;r++){
                float m = sacc[rb][0][r];
                #pragma unroll
                for (int nbi=1;nbi<8;nbi++) m = fmaxf(m, sacc[rb][nbi][r]);
                #pragma unroll
                for (int o=1;o<16;o<<=1) m = fmaxf(m, __shfl_xor(m, o));
                rmax[rb][r] = m;
            }
        if (lm==0){
            #pragma unroll
            for (int rb=0;rb<2;rb++)
                #pragma unroll
                for (int r=0;r<4;r++) Ss[w*32 + rb*16+kg*4+r] = rmax[rb][r];
        }
        __syncthreads();
        float gmax[2][4];
        #pragma unroll
        for (int rb=0;rb<2;rb++)
            #pragma unroll
            for (int r=0;r<4;r++){
                int row = rb*16+kg*4+r;
                gmax[rb][r] = fmaxf(fmaxf(Ss[row],Ss[32+row]), fmaxf(Ss[64+row],Ss[96+row]));
            }
        // exp + row sum
        float rsum[2][4];
        #pragma unroll
        for (int rb=0;rb<2;rb++)
            #pragma unroll
            for (int r=0;r<4;r++){
                float acc = 0.f;
                #pragma unroll
                for (int nbi=0;nbi<8;nbi++){
                    float e = __expf(sacc[rb][nbi][r] - gmax[rb][r]);
                    sacc[rb][nbi][r] = e;
                    acc += e;
                }
                #pragma unroll
                for (int o=1;o<16;o<<=1) acc += __shfl_xor(acc, o);
                rsum[rb][r] = acc;
            }
        if (lm==0){
            #pragma unroll
            for (int rb=0;rb<2;rb++)
                #pragma unroll
                for (int r=0;r<4;r++) Ss[128 + w*32 + rb*16+kg*4+r] = rsum[rb][r];
        }
        __syncthreads();
        float scl[2][4];
        #pragma unroll
        for (int rb=0;rb<2;rb++)
            #pragma unroll
            for (int r=0;r<4;r++){
                int row = rb*16+kg*4+r;
                float sm = (Ss[128+row]+Ss[160+row]) + (Ss[192+row]+Ss[224+row]);
                float g = gatt[((size_t)bh*512 + t0+row)*4 + c];
                scl[rb][r] = g / sm;
            }
        __syncthreads();                        // before overwriting Ss with P
        // p = g * e / sum -> global final_att + swizzled LDS (for A-frag reads)
        float* fabase = fa + ((size_t)bh*512 + t0)*2048 + c*512;
        #pragma unroll
        for (int rb=0;rb<2;rb++)
            #pragma unroll
            for (int nbi=0;nbi<8;nbi++)
                #pragma unroll
                for (int r=0;r<4;r++){
                    int row = rb*16+kg*4+r, col = w*128+nbi*16+lm;
                    float p = sacc[rb][nbi][r]*scl[rb][r];
                    fabase[(size_t)row*2048 + col] = p;
                    Ss[row*512 + (col ^ ((row&7)*8))] = p;
                }
        __syncthreads();
        // O += P @ V   (wave w owns e-cols (w*2+nbi)*16)
        const bf16* vbase = lvt + ((size_t)(c*8+b)*8 + h)*128*512;
        for (int kk=0;kk<16;kk++){
            short8 a8[2];
            #pragma unroll
            for (int rb=0;rb<2;rb++){
                int prow = rb*16 + lm;
                int pcol = (kk*32 + kg*8) ^ ((prow&7)*8);
                const float* sp = Ss + (size_t)prow*512 + pcol;
                floatx4 f0 = *(const floatx4*)sp;
                floatx4 f1 = *(const floatx4*)(sp+4);
                short8 a;
                a[0]=(short)f2bb(f0[0]); a[1]=(short)f2bb(f0[1]);
                a[2]=(short)f2bb(f0[2]); a[3]=(short)f2bb(f0[3]);
                a[4]=(short)f2bb(f1[0]); a[5]=(short)f2bb(f1[1]);
                a[6]=(short)f2bb(f1[2]); a[7]=(short)f2bb(f1[3]);
                a8[rb]=a;
            }
            #pragma unroll
            for (int nbi=0;nbi<2;nbi++){
                int e = (w*2+nbi)*16 + lm;
                short8 b8 = *(const short8*)(vbase + (size_t)e*512 + kk*32 + kg*8);
                oacc[0][nbi] = MFMA(a8[0], b8, oacc[0][nbi]);
                oacc[1][nbi] = MFMA(a8[1], b8, oacc[1][nbi]);
            }
        }
    }
    // store O (bf16) into out_head [b*T+t][h*128+e]
    #pragma unroll
    for (int nbi=0;nbi<2;nbi++)
        #pragma unroll
        for (int rb=0;rb<2;rb++)
            #pragma unroll
            for (int r=0;r<4;r++){
                int trow = t0 + rb*16 + kg*4 + r;
                int e = (w*2+nbi)*16 + lm;
                oh[((size_t)b*512 + trow)*1024 + h*128 + e] = __float2bfloat16(oacc[rb][nbi][r]);
            }
}

// ---------------- launch ----------------
extern "C" void kernel_launch(void* const* d_in, const int* in_sizes, int n_in,
                              void* d_out, int out_size, void* d_ws, size_t ws_size,
                              hipStream_t stream)
{
    const float* trg    = (const float*)d_in[0];
    const float* guider = (const float*)d_in[1];
    const float* low    = (const float*)d_in[2];
    const float* Wq     = (const float*)d_in[3];
    const float* Wkg    = (const float*)d_in[4];
    const float* Wkl    = (const float*)d_in[5];
    const float* Wvl    = (const float*)d_in[6];
    const float* Wfc    = (const float*)d_in[7];
    const float* gamma  = (const float*)d_in[8];
    const float* beta   = (const float*)d_in[9];
    const int*   gmask  = (const int*)d_in[10];
    const int*   lmask  = (const int*)d_in[11];
    float* out = (float*)d_out;
    float* fa  = out + (size_t)2097152;        // [B,H,T,2048]

    char* ws = (char*)d_ws;
    size_t off = 0;
    auto alloc = [&](size_t bytes)->void*{
        void* p = ws + off; off += (bytes + 255) & ~(size_t)255; return p;
    };
    bf16*  xln  = (bf16*) alloc((size_t)4096*512*2);
    bf16*  wqT  = (bf16*) alloc((size_t)1024*512*2);
    bf16*  wkT  = (bf16*) alloc((size_t)2*1024*512*2);
    bf16*  wvT  = (bf16*) alloc((size_t)2*1024*512*2);
    bf16*  wfT  = (bf16*) alloc((size_t)512*1024*2);
    bf16*  lowb = (bf16*) alloc((size_t)8388608*2);
    bf16*  qsb  = (bf16*) alloc((size_t)4194304*2);
    bf16*  lkb  = (bf16*) alloc((size_t)16777216*2);
    bf16*  lvtb = (bf16*) alloc((size_t)16777216*2);
    float* gkb  = (float*)alloc((size_t)32768*4);
    float* gattb= (float*)alloc((size_t)131072*4);
    bf16*  ohb  = (bf16*) alloc((size_t)4194304*2);

    conv_kernel<<<8192, 256, 0, stream>>>(low, lowb, 2097152);
    wtrans_kernel<<<dim3(32,16,1), dim3(32,8), 0, stream>>>(Wq,  wqT, 512, 1024);
    wtrans_kernel<<<dim3(32,16,2), dim3(32,8), 0, stream>>>(Wkl, wkT, 512, 1024);
    wtrans_kernel<<<dim3(32,16,2), dim3(32,8), 0, stream>>>(Wvl, wvT, 512, 1024);
    wtrans_kernel<<<dim3(16,32,1), dim3(32,8), 0, stream>>>(Wfc, wfT, 1024, 512);
    ln_kernel<<<4096, 256, 0, stream>>>(trg, gamma, beta, xln);
    gemm_k<0><<<dim3(8,32,1),  256, 0, stream>>>(xln,  wqT, qsb,  nullptr, 4096, 1024, 512);
    gk_kernel<<<32, 256, 0, stream>>>(guider, Wkg, gkb);
    gatt_kernel<<<128, 256, 0, stream>>>(qsb, gkb, gmask, gattb);
    gemm_k<1><<<dim3(8,64,2),  256, 0, stream>>>(lowb, wkT, lkb,  nullptr, 8192, 1024, 512);
    gemm_k<2><<<dim3(8,64,2),  256, 0, stream>>>(lowb, wvT, lvtb, nullptr, 8192, 1024, 512);
    attn_kernel<<<1024, 256, 0, stream>>>(qsb, lkb, lvtb, gattb, lmask, fa, ohb);
    gemm_k<3><<<dim3(4,32,1),  256, 0, stream>>>(ohb, wfT, out, trg, 4096, 512, 1024);
}

// Round 2
// 875.622 us; speedup vs baseline: 1.2753x; 1.2753x over previous
//
#include <hip/hip_runtime.h>
#include <hip/hip_bf16.h>

using bf16 = __hip_bfloat16;
typedef __attribute__((ext_vector_type(8))) short short8;
typedef __attribute__((ext_vector_type(4))) float floatx4;

#define MFMA(a,b,c) __builtin_amdgcn_mfma_f32_16x16x32_bf16(a,b,c,0,0,0)

static __device__ __forceinline__ unsigned short f2bb(float f){
    union { __hip_bfloat16 h; unsigned short u; } cv;
    cv.h = __float2bfloat16(f);
    return cv.u;
}

// ---------------- convert fp32 -> bf16 (vectorized) ----------------
__global__ __launch_bounds__(256) void conv_kernel(const float* __restrict__ in,
                                                   bf16* __restrict__ out, int n4){
    int i = blockIdx.x*256 + threadIdx.x;
    if (i < n4){
        float4 v = ((const float4*)in)[i];
        uint2 p;
        p.x = (unsigned)f2bb(v.x) | ((unsigned)f2bb(v.y) << 16);
        p.y = (unsigned)f2bb(v.z) | ((unsigned)f2bb(v.w) << 16);
        ((uint2*)out)[i] = p;
    }
}

// ---------------- weight transpose fp32[K][N] -> bf16[N][K] ----------------
__global__ __launch_bounds__(256) void wtrans_kernel(const float* __restrict__ in,
                                                     bf16* __restrict__ out, int K, int N){
    __shared__ float t[32][33];
    int z = blockIdx.z;
    in  += (size_t)z*K*N;
    out += (size_t)z*K*N;
    int n0 = blockIdx.x*32, k0 = blockIdx.y*32;
    int tx = threadIdx.x, ty = threadIdx.y;
    #pragma unroll
    for (int j=0;j<32;j+=8) t[ty+j][tx] = in[(size_t)(k0+ty+j)*N + n0+tx];
    __syncthreads();
    #pragma unroll
    for (int j=0;j<32;j+=8) out[(size_t)(n0+ty+j)*K + k0+tx] = __float2bfloat16(t[tx][ty+j]);
}

// ---------------- LayerNorm, row = 512 floats, out bf16 ----------------
__global__ __launch_bounds__(256) void ln_kernel(const float* __restrict__ x,
                                                 const float* __restrict__ g,
                                                 const float* __restrict__ bta,
                                                 bf16* __restrict__ out){
    int row = blockIdx.x;
    const float* xr = x + (size_t)row*512;
    int tid = threadIdx.x;
    float v0 = xr[tid], v1 = xr[tid+256];
    float s = v0 + v1;
    #pragma unroll
    for (int o=1;o<64;o<<=1) s += __shfl_xor(s, o);
    __shared__ float red[8];
    if ((tid&63)==0) red[tid>>6] = s;
    __syncthreads();
    float mean = (red[0]+red[1]+red[2]+red[3]) * (1.0f/512.0f);
    float d0 = v0-mean, d1 = v1-mean;
    float vs = d0*d0 + d1*d1;
    #pragma unroll
    for (int o=1;o<64;o<<=1) vs += __shfl_xor(vs, o);
    if ((tid&63)==0) red[4 + (tid>>6)] = vs;
    __syncthreads();
    float var = (red[4]+red[5]+red[6]+red[7]) * (1.0f/512.0f);
    float rstd = rsqrtf(var + 1e-6f);
    out[(size_t)row*512 + tid]     = __float2bfloat16(d0*rstd*g[tid]     + bta[tid]);
    out[(size_t)row*512 + tid+256] = __float2bfloat16(d1*rstd*g[tid+256] + bta[tid+256]);
}

// ---------------- guider keys, padded bf16 [b][h][16][128] (rows>=4 zero) ----
__global__ __launch_bounds__(256) void gkpad_kernel(const float* __restrict__ guider,
                                                    const float* __restrict__ Wkg,
                                                    bf16* __restrict__ gkpad){
    int cc = blockIdx.x;          // 0..3 (256-col chunk)
    int g  = blockIdx.y;          // 0..15 (padded row)
    int b  = blockIdx.z;          // 0..7
    int tid = threadIdx.x;
    int col = cc*256 + tid;       // 0..1023 = h*128+dk
    int h = col>>7, dk = col&127;
    bf16* outp = gkpad + (((size_t)(b*8+h))*16 + g)*128 + dk;
    if (g >= 4){ *outp = __float2bfloat16(0.f); return; }
    __shared__ float xr[512];
    xr[tid]     = guider[((size_t)b*4+g)*512 + tid];
    xr[tid+256] = guider[((size_t)b*4+g)*512 + tid+256];
    __syncthreads();
    int m = g>>1;
    const float* W = Wkg + (size_t)m*512*1024 + col;
    float a0=0,a1=0,a2=0,a3=0;
    for (int d=0; d<512; d+=4){
        a0 += xr[d]  *W[(size_t)d*1024];
        a1 += xr[d+1]*W[(size_t)(d+1)*1024];
        a2 += xr[d+2]*W[(size_t)(d+2)*1024];
        a3 += xr[d+3]*W[(size_t)(d+3)*1024];
    }
    *outp = __float2bfloat16((a0+a1)+(a2+a3));
}

// ---------------- generic 128x128 bf16 MFMA GEMM, C = A @ Bt^T ----------------
// A: [M][K] bf16 (k-contig), Bt: [N][K] bf16 (k-contig). blockIdx.z = modality.
// EPI 0: qs bf16 [B,H,T,DK] scaled 1/sqrt(128)
// EPI 1: lk bf16 [M,S,B,H,L,DK]
// EPI 2: lv^T bf16 [M,S,B,H,DV,L]
// EPI 3: out fp32 = acc + resid
template<int EPI>
__global__ __launch_bounds__(256)
void gemm_k(const bf16* __restrict__ A, const bf16* __restrict__ Bt,
            void* __restrict__ Cout, const float* __restrict__ resid,
            int M, int N, int K)
{
    int mz = blockIdx.z;
    A  += (size_t)mz * M * K;
    Bt += (size_t)mz * N * K;
    int m0 = blockIdx.y * 128, n0 = blockIdx.x * 128;
    __shared__ alignas(16) bf16 As[8192];   // [kb2][rb8][kg4][m16][j8]
    __shared__ alignas(16) bf16 Bs[8192];
    int tid = threadIdx.x;
    int wave = tid >> 6, lane = tid & 63, kg = lane >> 4, lm = lane & 15;
    int wr = wave >> 1, wc = wave & 1;
    floatx4 acc[4][4];
    #pragma unroll
    for (int i=0;i<4;i++)
        #pragma unroll
        for (int j=0;j<4;j++) acc[i][j] = (floatx4){0.f,0.f,0.f,0.f};

    for (int k0 = 0; k0 < K; k0 += 64){
        __syncthreads();
        #pragma unroll
        for (int i=0;i<4;i++){
            int idx = tid + i*256;
            int row = idx >> 3, kc = idx & 7;
            int lo = ((((kc>>2)*8 + (row>>4))*4 + (kc&3))*16 + (row&15))*8;
            *(short8*)(As + lo) = *(const short8*)(A  + (size_t)(m0+row)*K + k0 + kc*8);
            *(short8*)(Bs + lo) = *(const short8*)(Bt + (size_t)(n0+row)*K + k0 + kc*8);
        }
        __syncthreads();
        #pragma unroll
        for (int kb=0;kb<2;kb++){
            short8 af[4], bfr[4];
            #pragma unroll
            for (int i=0;i<4;i++){
                af[i]  = *(const short8*)(As + (((kb*8 + wr*4+i)*4 + kg)*16 + lm)*8);
                bfr[i] = *(const short8*)(Bs + (((kb*8 + wc*4+i)*4 + kg)*16 + lm)*8);
            }
            #pragma unroll
            for (int i=0;i<4;i++)
                #pragma unroll
                for (int j=0;j<4;j++)
                    acc[i][j] = MFMA(af[i], bfr[j], acc[i][j]);
        }
    }
    #pragma unroll
    for (int i=0;i<4;i++){
        #pragma unroll
        for (int j=0;j<4;j++){
            int row0 = m0 + wr*64 + i*16 + kg*4;
            int col  = n0 + wc*64 + j*16 + lm;
            if constexpr (EPI == 2){
                int s = row0 >> 12, b = (row0 >> 9) & 7, l = row0 & 511;
                int h = col >> 7, e = col & 127;
                size_t off = ((((size_t)(mz*2+s)*8+b)*8+h)*128 + e)*512 + l;
                uint2 pk;
                pk.x = (unsigned)f2bb(acc[i][j][0]) | ((unsigned)f2bb(acc[i][j][1])<<16);
                pk.y = (unsigned)f2bb(acc[i][j][2]) | ((unsigned)f2bb(acc[i][j][3])<<16);
                *(uint2*)((bf16*)Cout + off) = pk;
            } else {
                #pragma unroll
                for (int r=0;r<4;r++){
                    int row = row0 + r;
                    float v = acc[i][j][r];
                    if constexpr (EPI == 0){
                        int b = row>>9, t = row&511, h = col>>7, dk = col&127;
                        ((bf16*)Cout)[((size_t)(b*8+h)*512 + t)*128 + dk] =
                            __float2bfloat16(v*0.08838834764831845f);
                    } else if constexpr (EPI == 1){
                        int s = row>>12, b = (row>>9)&7, l = row&511;
                        int h = col>>7, dk = col&127;
                        ((bf16*)Cout)[((((size_t)(mz*2+s)*8+b)*8+h)*512 + l)*128 + dk] =
                            __float2bfloat16(v);
                    } else {
                        ((float*)Cout)[(size_t)row*512 + col] = v + resid[(size_t)row*512 + col];
                    }
                }
            }
        }
    }
}

// ---------------- fused attention, 16 Q-rows per block, guider att fused ----
// grid: blk = tb*64 + bh  (tb 0..31, bh 0..63) -> same (b,h) stays on one XCD.
// Per chunk c: S=QK^T (waves split the 512 L-cols), mask, softmax (LDS
// cross-wave reduce), P = g_att * softmax -> final_att (fp32 global) + bf16
// swizzled LDS, O += P@V. oacc accumulated across chunks.
__global__ __launch_bounds__(256,3)
void attn_kernel(const bf16* __restrict__ qs, const bf16* __restrict__ lk,
                 const bf16* __restrict__ lvt, const bf16* __restrict__ gkpad,
                 const int* __restrict__ gmask, const int* __restrict__ lmask,
                 float* __restrict__ fa, bf16* __restrict__ oh)
{
    __shared__ alignas(16) bf16 Ps[16*512];   // 16 KB P buffer, 16B-granule XOR swizzle
    __shared__ float red[128];                // [0..63] max, [64..127] sum
    int blk = blockIdx.x;
    int bh = blk & 63, tb = blk >> 6;
    int b = bh >> 3, h = bh & 7;
    int t0 = tb * 16;
    int tid = threadIdx.x, w = tid>>6, lane = tid&63, kg = lane>>4, lm = lane&15;

    // Q fragments: A[m=lm][k] for the 16-row tile
    const bf16* qbase = qs + ((size_t)bh*512 + t0)*128;
    short8 qf[4];
    #pragma unroll
    for (int kb=0;kb<4;kb++)
        qf[kb] = *(const short8*)(qbase + (size_t)lm*128 + kb*32 + kg*8);

    // guider scores: q @ gk^T (gk zero-padded to 16 rows); each wave redundant
    floatx4 gsc = (floatx4){0.f,0.f,0.f,0.f};
    const bf16* gkb = gkpad + (size_t)bh*2048;
    #pragma unroll
    for (int kb=0;kb<4;kb++){
        short8 gf = *(const short8*)(gkb + (size_t)lm*128 + kb*32 + kg*8);
        gsc = MFMA(qf[kb], gf, gsc);
    }
    // softmax over g = lm in 0..3 (width-4 shuffle groups); ga[r] valid at lm<4
    float ga[4];
    {
        const int* gm = gmask + ((size_t)b*512 + t0)*4;
        #pragma unroll
        for (int r=0;r<4;r++){
            float s = gsc[r];
            if (lm < 4 && gm[(kg*4+r)*4 + lm] == 0) s = -1e9f;
            float mx = fmaxf(s, __shfl_xor(s,1,4));
            mx = fmaxf(mx, __shfl_xor(mx,2,4));
            float e = __expf(s-mx);
            float su = e + __shfl_xor(e,1,4);
            su += __shfl_xor(su,2,4);
            ga[r] = e / su;
        }
    }

    floatx4 oacc[2];
    oacc[0] = (floatx4){0.f,0.f,0.f,0.f};
    oacc[1] = (floatx4){0.f,0.f,0.f,0.f};

    for (int c=0;c<4;c++){
        // ---- S = Q @ K^T  (wave w owns cols w*128..w*128+127)
        const bf16* kbase = lk + ((size_t)(c*8+b)*8 + h)*65536;
        floatx4 sacc[8];
        #pragma unroll
        for (int i=0;i<8;i++) sacc[i] = (floatx4){0.f,0.f,0.f,0.f};
        #pragma unroll
        for (int kb=0;kb<4;kb++)
            #pragma unroll
            for (int nbi=0;nbi<8;nbi++){
                int l = w*128 + nbi*16 + lm;
                short8 kf = *(const short8*)(kbase + (size_t)l*128 + kb*32 + kg*8);
                sacc[nbi] = MFMA(qf[kb], kf, sacc[nbi]);
            }
        // ---- mask
        const int* mbase = lmask + ((size_t)(c*8+b)*512 + t0)*512;
        #pragma unroll
        for (int nbi=0;nbi<8;nbi++)
            #pragma unroll
            for (int r=0;r<4;r++){
                int mv = mbase[(size_t)(kg*4+r)*512 + w*128 + nbi*16 + lm];
                if (mv == 0) sacc[nbi][r] = -1e9f;
            }
        // ---- row max (in-wave then cross-wave via LDS)
        float rv[4];
        #pragma unroll
        for (int r=0;r<4;r++){
            float m = sacc[0][r];
            #pragma unroll
            for (int nbi=1;nbi<8;nbi++) m = fmaxf(m, sacc[nbi][r]);
            #pragma unroll
            for (int o=1;o<16;o<<=1) m = fmaxf(m, __shfl_xor(m,o,16));
            rv[r] = m;
        }
        if (lm==0){
            #pragma unroll
            for (int r=0;r<4;r++) red[w*16 + kg*4 + r] = rv[r];
        }
        __syncthreads();
        // ---- exp + row sum
        #pragma unroll
        for (int r=0;r<4;r++){
            int row = kg*4+r;
            float gmx = fmaxf(fmaxf(red[row],red[16+row]),fmaxf(red[32+row],red[48+row]));
            float acc = 0.f;
            #pragma unroll
            for (int nbi=0;nbi<8;nbi++){
                float e = __expf(sacc[nbi][r]-gmx);
                sacc[nbi][r] = e;
                acc += e;
            }
            #pragma unroll
            for (int o=1;o<16;o<<=1) acc += __shfl_xor(acc,o,16);
            rv[r] = acc;
        }
        if (lm==0){
            #pragma unroll
            for (int r=0;r<4;r++) red[64 + w*16 + kg*4 + r] = rv[r];
        }
        __syncthreads();
        float scl[4];
        #pragma unroll
        for (int r=0;r<4;r++){
            int row = kg*4+r;
            float sm = (red[64+row]+red[80+row]) + (red[96+row]+red[112+row]);
            float g = __shfl(ga[r], kg*16 + c);      // g_att[row][c]
            scl[r] = g / sm;
        }
        // ---- P -> final_att (fp32) + swizzled bf16 LDS
        float* fabase = fa + ((size_t)bh*512 + t0)*2048 + c*512;
        #pragma unroll
        for (int nbi=0;nbi<8;nbi++)
            #pragma unroll
            for (int r=0;r<4;r++){
                int row = kg*4+r, col = w*128 + nbi*16 + lm;
                float p = sacc[nbi][r]*scl[r];
                fabase[(size_t)row*2048 + col] = p;
                Ps[row*512 + (((col>>3) ^ (row&7))*8) + (col&7)] = __float2bfloat16(p);
            }
        __syncthreads();
        // ---- O += P @ V   (wave w owns e-cols w*32..w*32+31)
        const bf16* vbase = lvt + ((size_t)(c*8+b)*8 + h)*65536;
        #pragma unroll
        for (int kk=0;kk<16;kk++){
            short8 a8 = *(const short8*)(Ps + (size_t)lm*512 + (((kk*4+kg) ^ (lm&7))*8));
            #pragma unroll
            for (int nbi=0;nbi<2;nbi++){
                int e = w*32 + nbi*16 + lm;
                short8 b8 = *(const short8*)(vbase + (size_t)e*512 + kk*32 + kg*8);
                oacc[nbi] = MFMA(a8, b8, oacc[nbi]);
            }
        }
        // next chunk's Ps/red writes are guarded by its own two syncthreads
    }
    // store O (bf16) into out_head [b*T+t][h*128+e]
    #pragma unroll
    for (int nbi=0;nbi<2;nbi++)
        #pragma unroll
        for (int r=0;r<4;r++){
            int trow = t0 + kg*4 + r, e = w*32 + nbi*16 + lm;
            oh[((size_t)b*512 + trow)*1024 + h*128 + e] = __float2bfloat16(oacc[nbi][r]);
        }
}

// ---------------- launch ----------------
extern "C" void kernel_launch(void* const* d_in, const int* in_sizes, int n_in,
                              void* d_out, int out_size, void* d_ws, size_t ws_size,
                              hipStream_t stream)
{
    const float* trg    = (const float*)d_in[0];
    const float* guider = (const float*)d_in[1];
    const float* low    = (const float*)d_in[2];
    const float* Wq     = (const float*)d_in[3];
    const float* Wkg    = (const float*)d_in[4];
    const float* Wkl    = (const float*)d_in[5];
    const float* Wvl    = (const float*)d_in[6];
    const float* Wfc    = (const float*)d_in[7];
    const float* gamma  = (const float*)d_in[8];
    const float* beta   = (const float*)d_in[9];
    const int*   gmask  = (const int*)d_in[10];
    const int*   lmask  = (const int*)d_in[11];
    float* out = (float*)d_out;
    float* fa  = out + (size_t)2097152;        // [B,H,T,2048]

    char* ws = (char*)d_ws;
    size_t off = 0;
    auto alloc = [&](size_t bytes)->void*{
        void* p = ws + off; off += (bytes + 255) & ~(size_t)255; return p;
    };
    bf16*  xln  = (bf16*) alloc((size_t)4096*512*2);
    bf16*  wqT  = (bf16*) alloc((size_t)1024*512*2);
    bf16*  wkT  = (bf16*) alloc((size_t)2*1024*512*2);
    bf16*  wvT  = (bf16*) alloc((size_t)2*1024*512*2);
    bf16*  wfT  = (bf16*) alloc((size_t)512*1024*2);
    bf16*  lowb = (bf16*) alloc((size_t)8388608*2);
    bf16*  qsb  = (bf16*) alloc((size_t)4194304*2);
    bf16*  lkb  = (bf16*) alloc((size_t)16777216*2);
    bf16*  lvtb = (bf16*) alloc((size_t)16777216*2);
    bf16*  gkp  = (bf16*) alloc((size_t)8*8*16*128*2);
    bf16*  ohb  = (bf16*) alloc((size_t)4194304*2);

    conv_kernel<<<8192, 256, 0, stream>>>(low, lowb, 2097152);
    wtrans_kernel<<<dim3(32,16,1), dim3(32,8), 0, stream>>>(Wq,  wqT, 512, 1024);
    wtrans_kernel<<<dim3(32,16,2), dim3(32,8), 0, stream>>>(Wkl, wkT, 512, 1024);
    wtrans_kernel<<<dim3(32,16,2), dim3(32,8), 0, stream>>>(Wvl, wvT, 512, 1024);
    wtrans_kernel<<<dim3(16,32,1), dim3(32,8), 0, stream>>>(Wfc, wfT, 1024, 512);
    ln_kernel<<<4096, 256, 0, stream>>>(trg, gamma, beta, xln);
    gkpad_kernel<<<dim3(4,16,8), 256, 0, stream>>>(guider, Wkg, gkp);
    gemm_k<0><<<dim3(8,32,1),  256, 0, stream>>>(xln,  wqT, qsb,  nullptr, 4096, 1024, 512);
    gemm_k<1><<<dim3(8,64,2),  256, 0, stream>>>(lowb, wkT, lkb,  nullptr, 8192, 1024, 512);
    gemm_k<2><<<dim3(8,64,2),  256, 0, stream>>>(lowb, wvT, lvtb, nullptr, 8192, 1024, 512);
    attn_kernel<<<2048, 256, 0, stream>>>(qsb, lkb, lvtb, gkp, gmask, lmask, fa, ohb);
    gemm_k<3><<<dim3(4,32,1),  256, 0, stream>>>(ohb, wfT, out, trg, 4096, 512, 1024);
}